// Round 12
// baseline (230.641 us; speedup 1.0000x reference)
//
#include <hip/hip_runtime.h>
#include <hip/hip_bf16.h>

typedef unsigned short ushort;
typedef __attribute__((ext_vector_type(8))) short short8;
typedef __attribute__((ext_vector_type(4))) float f32x4;

constexpr int N_  = 4096;
constexpr int TD_ = 768;
constexpr int ID_ = 512;
constexpr int H_  = 256;
constexpr int HD_ = 64;
constexpr int E_  = 131072;
constexpr int SPLITS = 8;
constexpr float QSCALE = 0.125f * 1.44269504088896f;  // 1/sqrt(64) * log2(e)

#define MFMA16(a, b, c) __builtin_amdgcn_mfma_f32_16x16x32_bf16(a, b, c, 0, 0, 0)

__device__ inline ushort f2bf(float x) {
    union { float f; unsigned u; } v; v.f = x;
    unsigned r = v.u + 0x7fff + ((v.u >> 16) & 1);
    return (ushort)(r >> 16);
}
__device__ inline float lo2f(unsigned u) { union { unsigned x; float f; } v; v.x = u << 16; return v.f; }
__device__ inline float hi2f(unsigned u) { union { unsigned x; float f; } v; v.x = u & 0xffff0000u; return v.f; }

__device__ inline float exp2r(float x) {
    float r;
    asm("v_exp_f32 %0, %1" : "=v"(r) : "v"(x));
    return r;
}
__device__ inline unsigned pkbf(float lo, float hi) {
    union { float f; unsigned u; } a, b; a.f = lo; b.f = hi;
    return __builtin_amdgcn_perm(b.u + 0x8000u, a.u + 0x8000u, 0x07060302u);
}

__device__ inline void gl_lds16(const void* g, void* l) {
    __builtin_amdgcn_global_load_lds((const __attribute__((address_space(1))) unsigned int*)g,
                                     (__attribute__((address_space(3))) unsigned int*)l, 16, 0, 0);
}

// Stage 64x64 bf16 tile into LDS (wave-uniform base + lane*16B), XOR-swizzled 16B chunks.
__device__ inline void stage64(const ushort* g, long long strideEl, ushort* lds, int w, int l) {
    int r8 = l >> 3;
    int cc = (l & 7) ^ r8;
    #pragma unroll
    for (int p = 0; p < 2; p++) {
        int row = w * 16 + p * 8 + r8;
        gl_lds16(g + (long long)row * strideEl + cc * 8, lds + (w * 16 + p * 8) * 64);
    }
}
// Stage 16x64 bf16 tile (B for 64x16 GEMM tiles): waves 0,1 cover 8 rows each. [verified R8/R9]
__device__ inline void stageB16(const ushort* g, long long strideEl, ushort* lds, int w, int l) {
    if (w < 2) {
        int r8 = l >> 3;
        int row = w * 8 + r8;
        int cc = (l & 7) ^ (row & 7);
        gl_lds16(g + (long long)row * strideEl + cc * 8, lds + w * 512);
    }
}
__device__ inline int swz(int row, int kOff) {
    return row * 64 + ((((kOff >> 3) ^ (row & 7))) << 3);
}

// ---------------- graph preprocessing ----------------

__global__ __launch_bounds__(256) void k_init(int* __restrict__ indeg, int* __restrict__ pos) {
    int i = blockIdx.x * 256 + threadIdx.x;
    indeg[i] = 0;
    pos[i] = 0;
}

// ---------------- prep: cvt (0..2591) | transposes (2592..2751) | edge count (2752..3263) ----------------

__global__ __launch_bounds__(256) void k_prep(const float* __restrict__ text, const float* __restrict__ img,
                                              const float* __restrict__ tw, const float* __restrict__ iw,
                                              const float* __restrict__ wq, const float* __restrict__ wk,
                                              const float* __restrict__ wv, const float* __restrict__ wo,
                                              const float* __restrict__ g1w, const float* __restrict__ g2w,
                                              const int* __restrict__ edst, int* __restrict__ indeg,
                                              ushort* __restrict__ textbf, ushort* __restrict__ imgbf,
                                              ushort* __restrict__ wobf,
                                              ushort* __restrict__ twT, ushort* __restrict__ iwT,
                                              ushort* __restrict__ wqT, ushort* __restrict__ wkT,
                                              ushort* __restrict__ wvT, ushort* __restrict__ g1wT,
                                              ushort* __restrict__ g2wT) {
    __shared__ float Ts[64][65];
    const int b = blockIdx.x;
    const int t = threadIdx.x;
    if (b >= 2752) {  // edge count
        int e = (b - 2752) * 256 + t;
        atomicAdd(&indeg[edst[e]], 1);
        return;
    }
    if (b < 2592) {  // linear bf16 cvt: text | img | wo
        size_t base = ((size_t)b * 256 + t) * 8;
        const size_t TXE = (size_t)N_ * TD_, IME = (size_t)N_ * ID_;
        const float* src; ushort* dst;
        if (base < TXE) { src = text + base; dst = textbf + base; }
        else if (base < TXE + IME) { src = img + (base - TXE); dst = imgbf + (base - TXE); }
        else { src = wo + (base - TXE - IME); dst = wobf + (base - TXE - IME); }
        float4 x = *(const float4*)src;
        float4 y = *(const float4*)(src + 4);
        ushort o[8] = { f2bf(x.x), f2bf(x.y), f2bf(x.z), f2bf(x.w),
                        f2bf(y.x), f2bf(y.y), f2bf(y.z), f2bf(y.w) };
        *(short8*)dst = *(const short8*)o;
        return;
    }
    int wb = b - 2592;
    const float* src; ushort* dst; int R, tile;
    if (wb < 48)       { src = tw;  dst = twT;  R = 768; tile = wb; }
    else if (wb < 80)  { src = iw;  dst = iwT;  R = 512; tile = wb - 48; }
    else if (wb < 96)  { src = wq;  dst = wqT;  R = 256; tile = wb - 80; }
    else if (wb < 112) { src = wk;  dst = wkT;  R = 256; tile = wb - 96; }
    else if (wb < 128) { src = wv;  dst = wvT;  R = 256; tile = wb - 112; }
    else if (wb < 144) { src = g1w; dst = g1wT; R = 256; tile = wb - 128; }
    else               { src = g2w; dst = g2wT; R = 256; tile = wb - 144; }
    const int r0 = (tile >> 2) * 64, c0 = (tile & 3) * 64;
    #pragma unroll
    for (int u = 0; u < 16; u++) {
        int lin = t + u * 256;
        int r = lin >> 6, c = lin & 63;
        Ts[r][c] = src[(size_t)(r0 + r) * 256 + c0 + c];
    }
    __syncthreads();
    #pragma unroll
    for (int u = 0; u < 16; u++) {
        int lin = t + u * 256;
        int c = lin >> 6, r = lin & 63;
        dst[(size_t)(c0 + c) * R + r0 + r] = f2bf(Ts[r][c]);
    }
}

// ---------------- combined projection 64x16 tiles (blocks 0..1023) + degree scan (block 1024) ----------------

__global__ __launch_bounds__(256, 4) void k_combined16(const ushort* __restrict__ text, const ushort* __restrict__ img,
                                                       const ushort* __restrict__ twT, const ushort* __restrict__ iwT,
                                                       const float* __restrict__ tb, const float* __restrict__ ib,
                                                       const int* __restrict__ indeg, int* __restrict__ offs,
                                                       float* __restrict__ dinv, ushort* __restrict__ out) {
    __shared__ ushort As[2][4096];
    __shared__ ushort Bs[2][1024];
    __shared__ ushort Cs[64 * 24];
    __shared__ int sums[256];
    const int b = blockIdx.x;
    const int t = threadIdx.x;
    if (b == 1024) {  // exclusive scan of indeg + dinv [verified R8]
        int v[16]; int ssum = 0; int base = t * 16;
        #pragma unroll
        for (int k2 = 0; k2 < 16; k2++) { v[k2] = indeg[base + k2]; ssum += v[k2]; }
        sums[t] = ssum;
        __syncthreads();
        for (int off = 1; off < 256; off <<= 1) {
            int x = (t >= off) ? sums[t - off] : 0;
            __syncthreads();
            sums[t] += x;
            __syncthreads();
        }
        int excl = sums[t] - ssum;
        #pragma unroll
        for (int k2 = 0; k2 < 16; k2++) {
            offs[base + k2] = excl;
            excl += v[k2];
            dinv[base + k2] = 1.f / sqrtf((float)(v[k2] + 1));
        }
        return;
    }
    const int bm = (b >> 4) * 64, bn = (b & 15) * 16;
    const int w = t >> 6, l = t & 63, q = l >> 4, i = l & 15;
    f32x4 acc1 = {0, 0, 0, 0}, acc2 = {0, 0, 0, 0};
    auto stC = [&](int c, int buf) {
        if (c < 12) {
            stage64(text + (size_t)bm * TD_ + c * 64, TD_, As[buf], w, l);
            stageB16(twT + (size_t)bn * TD_ + c * 64, TD_, Bs[buf], w, l);
        } else {
            stage64(img + (size_t)bm * ID_ + (c - 12) * 64, ID_, As[buf], w, l);
            stageB16(iwT + (size_t)bn * ID_ + (c - 12) * 64, ID_, Bs[buf], w, l);
        }
    };
    stC(0, 0);
    for (int c = 0; c < 20; c++) {
        __syncthreads();
        if (c + 1 < 20) stC(c + 1, (c + 1) & 1);
        const ushort* Ab = As[c & 1];
        const ushort* Bb = Bs[c & 1];
        #pragma unroll
        for (int kb = 0; kb < 2; kb++) {
            short8 af = *(const short8*)&Ab[swz(w * 16 + i, kb * 32 + q * 8)];
            short8 bfr = *(const short8*)&Bb[swz(i, kb * 32 + q * 8)];
            if (c < 12) acc1 = MFMA16(af, bfr, acc1);
            else        acc2 = MFMA16(af, bfr, acc2);
        }
    }
    __syncthreads();
    float b1 = tb[bn + i], b2 = ib[bn + i];
    #pragma unroll
    for (int r = 0; r < 4; r++) {
        float v = fmaxf(acc1[r] + b1, 0.f) + fmaxf(acc2[r] + b2, 0.f);
        Cs[(w * 16 + q * 4 + r) * 24 + i] = f2bf(v);
    }
    __syncthreads();
    if (t < 128) {
        int row = t >> 1, h8 = (t & 1) * 8;
        *(short8*)(out + (size_t)(bm + row) * H_ + bn + h8) = *(const short8*)&Cs[row * 24 + h8];
    }
}

// ---------------- QKV (blocks 0..767) + edge scatter (768..1279) + wo-fold (1280..1296) ----------------

__global__ __launch_bounds__(256) void k_qkv_scatfold(const ushort* __restrict__ A,
                                                      const ushort* __restrict__ WqT, const ushort* __restrict__ WkT,
                                                      const ushort* __restrict__ WvT,
                                                      const float* __restrict__ bq, const float* __restrict__ bk,
                                                      const float* __restrict__ bv,
                                                      ushort* __restrict__ Qg, ushort* __restrict__ Kg,
                                                      ushort* __restrict__ Vtg,
                                                      const int* __restrict__ esrc, const int* __restrict__ edst,
                                                      const int* __restrict__ offs, const float* __restrict__ dinv,
                                                      int* __restrict__ pos, int* __restrict__ ssrc,
                                                      float* __restrict__ swv,
                                                      const ushort* __restrict__ g1wT, const ushort* __restrict__ wobf,
                                                      const float* __restrict__ bo,
                                                      ushort* __restrict__ WpT, float* __restrict__ bp) {
    __shared__ ushort As[2][4096];
    __shared__ ushort Bs[2][4096];
    __shared__ ushort Cs[64 * 72];
    const int b = blockIdx.x;
    const int t = threadIdx.x;
    const int w = t >> 6, l = t & 63, q = l >> 4, i = l & 15;

    if (b >= 768) {
        if (b < 1280) {  // edge scatter
            int e = (b - 768) * 256 + t;
            int s = esrc[e], d = edst[e];
            int p = atomicAdd(&pos[d], 1);
            int idx = offs[d] + p;
            ssrc[idx] = s;
            swv[idx] = dinv[s] * dinv[d];
            return;
        }
        if (b == 1296) {  // bp[c] = sum_m bo[m] * g1wT[c][m]
            float acc = 0.f;
            const ushort* row = g1wT + (size_t)t * 256;
            for (int m8 = 0; m8 < 256; m8 += 8) {
                #pragma unroll
                for (int j = 0; j < 8; j++) acc += bo[m8 + j] * lo2f(((unsigned)row[m8 + j]) << 16);
            }
            bp[t] = acc;
            return;
        }
        // wo-fold tile: WpT[a][b2] = sum_m g1wT[a][m]*wobf[b2][m]
        const int f = b - 1280;
        const int bm = (f >> 2) * 64, bn = (f & 3) * 64;
        f32x4 acc[4];
        #pragma unroll
        for (int nt = 0; nt < 4; nt++) acc[nt] = (f32x4){0, 0, 0, 0};
        stage64(g1wT + (size_t)bm * H_, H_, As[0], w, l);
        stage64(wobf + (size_t)bn * H_, H_, Bs[0], w, l);
        for (int c = 0; c < 4; c++) {
            __syncthreads();
            if (c < 3) {
                stage64(g1wT + (size_t)bm * H_ + (c + 1) * 64, H_, As[(c + 1) & 1], w, l);
                stage64(wobf + (size_t)bn * H_ + (c + 1) * 64, H_, Bs[(c + 1) & 1], w, l);
            }
            const ushort* Ab = As[c & 1];
            const ushort* Bb = Bs[c & 1];
            #pragma unroll
            for (int kb = 0; kb < 2; kb++) {
                short8 af = *(const short8*)&Ab[swz(w * 16 + i, kb * 32 + q * 8)];
                #pragma unroll
                for (int nt = 0; nt < 4; nt++) {
                    short8 bfr = *(const short8*)&Bb[swz(nt * 16 + i, kb * 32 + q * 8)];
                    acc[nt] = MFMA16(af, bfr, acc[nt]);
                }
            }
        }
        __syncthreads();
        #pragma unroll
        for (int nt = 0; nt < 4; nt++)
            #pragma unroll
            for (int r = 0; r < 4; r++)
                Cs[(w * 16 + q * 4 + r) * 72 + nt * 16 + i] = f2bf(acc[nt][r]);
        __syncthreads();
        int rr = t >> 2, c16 = (t & 3) * 16;
        short8 v0 = *(const short8*)&Cs[rr * 72 + c16];
        short8 v1 = *(const short8*)&Cs[rr * 72 + c16 + 8];
        ushort* dstp = WpT + (size_t)(bm + rr) * H_ + bn + c16;
        *(short8*)dstp = v0;
        *(short8*)(dstp + 8) = v1;
        return;
    }

    // QKV: z = b>>8, rem = b&255 [verified R8]
    const int z = b >> 8, rem = b & 255;
    const int bm = (rem >> 2) * 64, head = rem & 3;
    const ushort* WT = (z == 0) ? WqT : (z == 1) ? WkT : WvT;
    const float* bias = (z == 0) ? bq : (z == 1) ? bk : bv;
    f32x4 acc[4];
    #pragma unroll
    for (int nt = 0; nt < 4; nt++) acc[nt] = (f32x4){0, 0, 0, 0};

    stage64(A + (size_t)bm * H_, H_, As[0], w, l);
    stage64(WT + (size_t)(head * 64) * H_, H_, Bs[0], w, l);
    for (int c = 0; c < 4; c++) {
        __syncthreads();
        if (c < 3) {
            stage64(A + (size_t)bm * H_ + (c + 1) * 64, H_, As[(c + 1) & 1], w, l);
            stage64(WT + (size_t)(head * 64) * H_ + (c + 1) * 64, H_, Bs[(c + 1) & 1], w, l);
        }
        const ushort* Ab = As[c & 1];
        const ushort* Bb = Bs[c & 1];
        #pragma unroll
        for (int kb = 0; kb < 2; kb++) {
            short8 af = *(const short8*)&Ab[swz(w * 16 + i, kb * 32 + q * 8)];
            #pragma unroll
            for (int nt = 0; nt < 4; nt++) {
                short8 bfr = *(const short8*)&Bb[swz(nt * 16 + i, kb * 32 + q * 8)];
                acc[nt] = MFMA16(af, bfr, acc[nt]);
            }
        }
    }
    __syncthreads();
    #pragma unroll
    for (int nt = 0; nt < 4; nt++) {
        float bv_ = bias[head * 64 + nt * 16 + i];
        #pragma unroll
        for (int r = 0; r < 4; r++) {
            float v = acc[nt][r] + bv_;
            if (z == 0) v *= QSCALE;
            if (z < 2) Cs[(w * 16 + q * 4 + r) * 72 + nt * 16 + i] = f2bf(v);
            else       Cs[(nt * 16 + i) * 72 + w * 16 + q * 4 + r] = f2bf(v);  // transposed [d][n]
        }
    }
    __syncthreads();
    int rr = t >> 2, c16 = (t & 3) * 16;
    short8 v0 = *(const short8*)&Cs[rr * 72 + c16];
    short8 v1 = *(const short8*)&Cs[rr * 72 + c16 + 8];
    ushort* dst;
    if (z < 2) dst = ((z == 0) ? Qg : Kg) + (size_t)head * N_ * HD_ + (size_t)(bm + rr) * HD_ + c16;
    else       dst = Vtg + (size_t)head * HD_ * N_ + (size_t)rr * N_ + bm + c16;
    *(short8*)dst = v0;
    *(short8*)(dst + 8) = v1;
}

// ---------------- flash attention: S^T math, single-buf K/V, split-8, 128 queries/block ----------------
// Per KV tile, the staged K/V and kf/vf ds_reads are reused across TWO query tiles: per-query
// staging traffic and barrier count halve vs the R9 64-query version. Ps reused sequentially
// per query tile (per-wave region, in-wave lgkmcnt ordering).

__global__ __launch_bounds__(256) void k_attn_mfma(const ushort* __restrict__ Qg, const ushort* __restrict__ Kg,
                                                   const ushort* __restrict__ Vtg, ushort* __restrict__ Op,
                                                   float* __restrict__ lp) {
    __shared__ ushort Ks[4096];
    __shared__ ushort Vs[4096];
    __shared__ ushort Ps[4][16 * 72];
    const int head = blockIdx.y, r0 = blockIdx.x * 128, z = blockIdx.z;
    const int t = threadIdx.x, w = t >> 6, l = t & 63, q = l >> 4, i = l & 15;
    const int rw = (i ^ (i >> 1)) & 7;
    ushort* Pw = &Ps[w][0];

    short8 qf[2][2];  // [qt][kb]
    #pragma unroll
    for (int qt = 0; qt < 2; qt++)
        #pragma unroll
        for (int kb = 0; kb < 2; kb++)
            qf[qt][kb] = *(const short8*)(Qg + ((size_t)head * N_ + r0 + qt * 64 + w * 16 + i) * HD_ + kb * 32 + q * 8);

    f32x4 Oacc[2][4];
    float lacc[2] = {0.f, 0.f};
    #pragma unroll
    for (int qt = 0; qt < 2; qt++)
        #pragma unroll
        for (int dt = 0; dt < 4; dt++) Oacc[qt][dt] = (f32x4){0, 0, 0, 0};

    const int NT = 64 / SPLITS;
    const int cb0 = z * NT;
    for (int it = 0; it < NT; it++) {
        const int cb = cb0 + it;
        __syncthreads();
        stage64(Kg + ((size_t)head * N_ + (size_t)cb * 64) * HD_, HD_, Ks, w, l);
        stage64(Vtg + (size_t)head * HD_ * N_ + cb * 64, N_, Vs, w, l);
        __syncthreads();

        // S^T for both query tiles; kf loaded once, used twice
        f32x4 St[2][4];
        #pragma unroll
        for (int qt = 0; qt < 2; qt++)
            #pragma unroll
            for (int kt = 0; kt < 4; kt++) St[qt][kt] = (f32x4){0, 0, 0, 0};
        #pragma unroll
        for (int kb = 0; kb < 2; kb++) {
            #pragma unroll
            for (int kt = 0; kt < 4; kt++) {
                short8 kf = *(const short8*)&Ks[swz(kt * 16 + i, kb * 32 + q * 8)];
                St[0][kt] = MFMA16(kf, qf[0][kb], St[0][kt]);
                St[1][kt] = MFMA16(kf, qf[1][kb], St[1][kt]);
            }
        }
        // per query tile: exp -> pack -> Ps -> PV (vf ds_reads repeated per qt; K-frag reuse is the win)
        #pragma unroll
        for (int qt = 0; qt < 2; qt++) {
            #pragma unroll
            for (int kt = 0; kt < 4; kt++) {
                float p0 = exp2r(St[qt][kt][0]), p1 = exp2r(St[qt][kt][1]);
                float p2 = exp2r(St[qt][kt][2]), p3 = exp2r(St[qt][kt][3]);
                lacc[qt] += (p0 + p1) + (p2 + p3);
                int off = i * 72 + (((2 * kt + (q >> 1)) ^ rw) << 3) + ((q & 1) << 2);
                uint2 v; v.x = pkbf(p0, p1); v.y = pkbf(p2, p3);
                *(uint2*)&Pw[off] = v;
            }
            #pragma unroll
            for (int kb = 0; kb < 2; kb++) {
                short8 pf = *(const short8*)&Pw[i * 72 + (((4 * kb + q) ^ rw) << 3)];
                #pragma unroll
                for (int dt = 0; dt < 4; dt++) {
                    short8 vf = *(const short8*)&Vs[swz(dt * 16 + i, kb * 32 + q * 8)];
                    Oacc[qt][dt] = MFMA16(vf, pf, Oacc[qt][dt]);
                }
            }
        }
    }

    #pragma unroll
    for (int qt = 0; qt < 2; qt++) {
        lacc[qt] += __shfl_xor(lacc[qt], 16);
        lacc[qt] += __shfl_xor(lacc[qt], 32);
    }

    const size_t sh = ((size_t)z * 4 + head) * N_;
    #pragma unroll
    for (int qt = 0; qt < 2; qt++) {
        const int row = r0 + qt * 64 + w * 16 + i;
        #pragma unroll
        for (int dt = 0; dt < 4; dt++) {
            uint2 v;
            v.x = pkbf(Oacc[qt][dt][0], Oacc[qt][dt][1]);
            v.y = pkbf(Oacc[qt][dt][2], Oacc[qt][dt][3]);
            *(uint2*)&Op[(sh + row) * HD_ + dt * 16 + q * 4] = v;
        }
        if (l < 16) lp[sh + r0 + qt * 64 + w * 16 + l] = lacc[qt];
    }
}

// merge 8 splits -> obuf bf16 [N][H]
__global__ __launch_bounds__(256) void k_attn_merge(const ushort* __restrict__ Op, const float* __restrict__ lp,
                                                    ushort* __restrict__ obuf) {
    const int t = threadIdx.x;
    const int idx = blockIdx.x * 16 + (t >> 4);
    const int h = idx >> 12, n = idx & 4095;
    const int d4 = (t & 15) * 4;
    float lsum = 0.f;
    float acc[4] = {0.f, 0.f, 0.f, 0.f};
    #pragma unroll
    for (int s = 0; s < SPLITS; s++) {
        size_t sh = ((size_t)s * 4 + h) * N_ + n;
        lsum += lp[sh];
        uint2 o4 = *(const uint2*)&Op[sh * HD_ + d4];
        acc[0] += lo2f(o4.x); acc[1] += hi2f(o4.x);
        acc[2] += lo2f(o4.y); acc[3] += hi2f(o4.y);
    }
    float inv = 1.f / lsum;
    uint2 res;
    res.x = pkbf(acc[0] * inv, acc[1] * inv);
    res.y = pkbf(acc[2] * inv, acc[3] * inv);
    *(uint2*)&obuf[(size_t)n * H_ + h * HD_ + d4] = res;
}

// ---------------- bf16 MFMA GEMM, 64x16 tiles (grid 64x16) [verified R9] ----------------

template <bool BIAS>
__global__ __launch_bounds__(256, 4) void k_gemm16(const ushort* __restrict__ A, const ushort* __restrict__ BT,
                                                   const float* __restrict__ bias, ushort* __restrict__ outb) {
    __shared__ ushort As[2][4096];
    __shared__ ushort Bs[2][1024];
    __shared__ ushort Cs[64 * 24];
    const int bm = blockIdx.x * 64, bn = blockIdx.y * 16;
    const int t = threadIdx.x, w = t >> 6, l = t & 63, q = l >> 4, i = l & 15;
    f32x4 acc = {0, 0, 0, 0};
    stage64(A + (size_t)bm * H_, H_, As[0], w, l);
    stageB16(BT + (size_t)bn * H_, H_, Bs[0], w, l);
    for (int c = 0; c < 4; c++) {
        __syncthreads();
        if (c < 3) {
            stage64(A + (size_t)bm * H_ + (c + 1) * 64, H_, As[(c + 1) & 1], w, l);
            stageB16(BT + (size_t)bn * H_ + (c + 1) * 64, H_, Bs[(c + 1) & 1], w, l);
        }
        const ushort* Ab = As[c & 1];
        const ushort* Bb = Bs[c & 1];
        #pragma unroll
        for (int kb = 0; kb < 2; kb++) {
            short8 af = *(const short8*)&Ab[swz(w * 16 + i, kb * 32 + q * 8)];
            short8 bfr = *(const short8*)&Bb[swz(i, kb * 32 + q * 8)];
            acc = MFMA16(af, bfr, acc);
        }
    }
    __syncthreads();
    float bb = BIAS ? bias[bn + i] : 0.f;
    #pragma unroll
    for (int r = 0; r < 4; r++)
        Cs[(w * 16 + q * 4 + r) * 24 + i] = f2bf(acc[r] + bb);
    __syncthreads();
    if (t < 128) {
        int row = t >> 1, h8 = (t & 1) * 8;
        *(short8*)(outb + (size_t)(bm + row) * H_ + bn + h8) = *(const short8*)&Cs[row * 24 + h8];
    }
}

// ---------------- GCN aggregation: one wave per node, 4 nodes/block ----------------

__global__ __launch_bounds__(256) void k_agg1(const ushort* __restrict__ h, const int* __restrict__ ssrc,
                                              const float* __restrict__ sw, const int* __restrict__ offs,
                                              const int* __restrict__ indeg, const float* __restrict__ dinv,
                                              const float* __restrict__ bias, ushort* __restrict__ outb) {
    const int t = threadIdx.x;
    const int j = __builtin_amdgcn_readfirstlane(blockIdx.x * 4 + (t >> 6));
    const int d0 = (t & 63) * 4;
    float dj = dinv[j];
    uint2 hv = *(const uint2*)&h[(size_t)j * H_ + d0];
    float s2 = dj * dj;
    float a0 = s2 * lo2f(hv.x), a1 = s2 * hi2f(hv.x), a2 = s2 * lo2f(hv.y), a3 = s2 * hi2f(hv.y);
    int start = offs[j], cnt = indeg[j];
    for (int e = 0; e < cnt; e++) {
        int s = ssrc[start + e];
        float wg = sw[start + e];
        uint2 v = *(const uint2*)&h[(size_t)s * H_ + d0];
        a0 += wg * lo2f(v.x); a1 += wg * hi2f(v.x);
        a2 += wg * lo2f(v.y); a3 += wg * hi2f(v.y);
    }
    a0 = fmaxf(a0 + bias[d0], 0.f);
    a1 = fmaxf(a1 + bias[d0 + 1], 0.f);
    a2 = fmaxf(a2 + bias[d0 + 2], 0.f);
    a3 = fmaxf(a3 + bias[d0 + 3], 0.f);
    uint2 o;
    o.x = pkbf(a0, a1);
    o.y = pkbf(a2, a3);
    *(uint2*)&outb[(size_t)j * H_ + d0] = o;
}

// ---------------- GCN layer 2 aggregation fused with classifier ----------------

__global__ __launch_bounds__(256) void k_aggcls(const ushort* __restrict__ h, const int* __restrict__ ssrc,
                                                const float* __restrict__ sw, const int* __restrict__ offs,
                                                const int* __restrict__ indeg, const float* __restrict__ dinv,
                                                const float* __restrict__ bias, const float* __restrict__ cw,
                                                const float* __restrict__ cb, float* __restrict__ out) {
    const int t = threadIdx.x;
    const int j = __builtin_amdgcn_readfirstlane(blockIdx.x * 4 + (t >> 6));
    const int lane = t & 63;
    const int d0 = lane * 4;
    float dj = dinv[j];
    uint2 hv = *(const uint2*)&h[(size_t)j * H_ + d0];
    float s2 = dj * dj;
    float a0 = s2 * lo2f(hv.x), a1 = s2 * hi2f(hv.x), a2 = s2 * lo2f(hv.y), a3 = s2 * hi2f(hv.y);
    int start = offs[j], cnt = indeg[j];
    for (int e = 0; e < cnt; e++) {
        int s = ssrc[start + e];
        float wg = sw[start + e];
        uint2 v = *(const uint2*)&h[(size_t)s * H_ + d0];
        a0 += wg * lo2f(v.x); a1 += wg * hi2f(v.x);
        a2 += wg * lo2f(v.y); a3 += wg * hi2f(v.y);
    }
    a0 += bias[d0]; a1 += bias[d0 + 1]; a2 += bias[d0 + 2]; a3 += bias[d0 + 3];
    float p0 = a0 * cw[d0 * 3 + 0] + a1 * cw[(d0 + 1) * 3 + 0]
             + a2 * cw[(d0 + 2) * 3 + 0] + a3 * cw[(d0 + 3) * 3 + 0];
    float p1 = a0 * cw[d0 * 3 + 1] + a1 * cw[(d0 + 1) * 3 + 1]
             + a2 * cw[(d0 + 2) * 3 + 1] + a3 * cw[(d0 + 3) * 3 + 1];
    float p2 = a0 * cw[d0 * 3 + 2] + a1 * cw[(d0 + 1) * 3 + 2]
             + a2 * cw[(d0 + 2) * 3 + 2] + a3 * cw[(d0 + 3) * 3 + 2];
    #pragma unroll
    for (int off = 32; off > 0; off >>= 1) {
        p0 += __shfl_xor(p0, off);
        p1 += __shfl_xor(p1, off);
        p2 += __shfl_xor(p2, off);
    }
    if (lane == 0) {
        out[j * 3 + 0] = p0 + cb[0];
        out[j * 3 + 1] = p1 + cb[1];
        out[j * 3 + 2] = p2 + cb[2];
    }
}

// ---------------- launch ----------------

extern "C" void kernel_launch(void* const* d_in, const int* in_sizes, int n_in,
                              void* d_out, int out_size, void* d_ws, size_t ws_size,
                              hipStream_t stream) {
    const float* text = (const float*)d_in[0];
    const float* img  = (const float*)d_in[1];
    const int*   eidx = (const int*)d_in[2];
    const float* tw  = (const float*)d_in[3];
    const float* tb  = (const float*)d_in[4];
    const float* iw  = (const float*)d_in[5];
    const float* ib  = (const float*)d_in[6];
    const float* wq  = (const float*)d_in[7];
    const float* bq  = (const float*)d_in[8];
    const float* wk  = (const float*)d_in[9];
    const float* bk  = (const float*)d_in[10];
    const float* wv  = (const float*)d_in[11];
    const float* bv  = (const float*)d_in[12];
    const float* wo  = (const float*)d_in[13];
    const float* bo  = (const float*)d_in[14];
    const float* g1w = (const float*)d_in[15];
    const float* g1b = (const float*)d_in[16];
    const float* g2w = (const float*)d_in[17];
    const float* g2b = (const float*)d_in[18];
    const float* cw  = (const float*)d_in[19];
    const float* cbv = (const float*)d_in[20];

    char* W = (char*)d_ws;
    size_t cur = 0;
    auto alloc = [&](size_t sz) { char* p = W + cur; cur += (sz + 255) & ~(size_t)255; return p; };

    // persistent region
    float* dinv  = (float*)alloc(N_ * 4);
    float* swv   = (float*)alloc(E_ * 4);
    int* indeg   = (int*)alloc(N_ * 4);
    int* offs    = (int*)alloc(N_ * 4);
    int* pos     = (int*)alloc(N_ * 4);
    int* ssrc    = (int*)alloc(E_ * 4);
    ushort* Qg   = (ushort*)alloc((size_t)N_ * H_ * 2);
    ushort* Kg   = (ushort*)alloc((size_t)N_ * H_ * 2);
    ushort* Vtg  = (ushort*)alloc((size_t)N_ * H_ * 2);
    ushort* obuf = (ushort*)alloc((size_t)N_ * H_ * 2);
    ushort* WpT  = (ushort*)alloc((size_t)H_ * H_ * 2);
    float* bp    = (float*)alloc(H_ * 4);
    ushort* g1wT = (ushort*)alloc((size_t)H_ * H_ * 2);
    ushort* g2wT = (ushort*)alloc((size_t)H_ * H_ * 2);
    ushort* wobf = (ushort*)alloc((size_t)H_ * H_ * 2);
    float* lp    = (float*)alloc((size_t)SPLITS * 4 * N_ * 4);
    char* S = W + cur;  // phase-overlaid scratch

    // phase 1: conversions + projections (~13 MB)
    ushort* textbf = (ushort*)S;
    ushort* imgbf  = textbf + (size_t)N_ * TD_;
    ushort* twT    = imgbf + (size_t)N_ * ID_;
    ushort* iwT    = twT + (size_t)TD_ * H_;
    ushort* wqT    = iwT + (size_t)ID_ * H_;
    ushort* wkT    = wqT + (size_t)H_ * H_;
    ushort* wvT    = wkT + (size_t)H_ * H_;
    ushort* combbf = wvT + (size_t)H_ * H_;
    // phase 2: Op = 8*4*N*64 bf16 = 16 MB (overlays phase 1)
    ushort* Op = (ushort*)S;
    // phase 3: post-attention (Op dead after merge)
    ushort* hbuf  = (ushort*)S;
    ushort* g1b16 = (ushort*)(S + (size_t)2 * 1024 * 1024);
    ushort* hbuf2 = (ushort*)(S + (size_t)4 * 1024 * 1024);

    const int* esrc = eidx;
    const int* edst = eidx + E_;

    k_init<<<dim3(N_ / 256), dim3(256), 0, stream>>>(indeg, pos);
    k_prep<<<dim3(3264), dim3(256), 0, stream>>>(text, img, tw, iw, wq, wk, wv, wo, g1w, g2w,
                                                 edst, indeg,
                                                 textbf, imgbf, wobf, twT, iwT, wqT, wkT, wvT, g1wT, g2wT);
    k_combined16<<<dim3(1025), dim3(256), 0, stream>>>(textbf, imgbf, twT, iwT, tb, ib,
                                                       indeg, offs, dinv, combbf);
    k_qkv_scatfold<<<dim3(1297), dim3(256), 0, stream>>>(combbf, wqT, wkT, wvT, bq, bk, bv, Qg, Kg, Vtg,
                                                         esrc, edst, offs, dinv, pos, ssrc, swv,
                                                         g1wT, wobf, bo, WpT, bp);
    k_attn_mfma<<<dim3(32, 4, SPLITS), dim3(256), 0, stream>>>(Qg, Kg, Vtg, Op, lp);
    k_attn_merge<<<dim3(1024), dim3(256), 0, stream>>>(Op, lp, obuf);

    k_gemm16<true><<<dim3(64, 16), dim3(256), 0, stream>>>(obuf, WpT, bp, hbuf);
    k_agg1<<<dim3(N_ / 4), dim3(256), 0, stream>>>(hbuf, ssrc, swv, offs, indeg, dinv, g1b, g1b16);
    k_gemm16<false><<<dim3(64, 16), dim3(256), 0, stream>>>(g1b16, g2wT, nullptr, hbuf2);
    k_aggcls<<<dim3(N_ / 4), dim3(256), 0, stream>>>(hbuf2, ssrc, swv, offs, indeg, dinv, g2b, cw, cbv,
                                                     (float*)d_out);
}

// Round 13
// 228.950 us; speedup vs baseline: 1.0074x; 1.0074x over previous
//
#include <hip/hip_runtime.h>
#include <hip/hip_bf16.h>

typedef unsigned short ushort;
typedef __attribute__((ext_vector_type(8))) short short8;
typedef __attribute__((ext_vector_type(4))) float f32x4;

constexpr int N_  = 4096;
constexpr int TD_ = 768;
constexpr int ID_ = 512;
constexpr int H_  = 256;
constexpr int HD_ = 64;
constexpr int E_  = 131072;
constexpr int SPLITS = 16;
constexpr float QSCALE = 0.125f * 1.44269504088896f;  // 1/sqrt(64) * log2(e)

#define MFMA16(a, b, c) __builtin_amdgcn_mfma_f32_16x16x32_bf16(a, b, c, 0, 0, 0)

__device__ inline ushort f2bf(float x) {
    union { float f; unsigned u; } v; v.f = x;
    unsigned r = v.u + 0x7fff + ((v.u >> 16) & 1);
    return (ushort)(r >> 16);
}
__device__ inline float lo2f(unsigned u) { union { unsigned x; float f; } v; v.x = u << 16; return v.f; }
__device__ inline float hi2f(unsigned u) { union { unsigned x; float f; } v; v.x = u & 0xffff0000u; return v.f; }

__device__ inline float exp2r(float x) {
    float r;
    asm("v_exp_f32 %0, %1" : "=v"(r) : "v"(x));
    return r;
}
__device__ inline unsigned pkbf(float lo, float hi) {
    union { float f; unsigned u; } a, b; a.f = lo; b.f = hi;
    return __builtin_amdgcn_perm(b.u + 0x8000u, a.u + 0x8000u, 0x07060302u);
}

__device__ inline void gl_lds16(const void* g, void* l) {
    __builtin_amdgcn_global_load_lds((const __attribute__((address_space(1))) unsigned int*)g,
                                     (__attribute__((address_space(3))) unsigned int*)l, 16, 0, 0);
}

// Stage 64x64 bf16 tile into LDS (wave-uniform base + lane*16B), XOR-swizzled 16B chunks.
__device__ inline void stage64(const ushort* g, long long strideEl, ushort* lds, int w, int l) {
    int r8 = l >> 3;
    int cc = (l & 7) ^ r8;
    #pragma unroll
    for (int p = 0; p < 2; p++) {
        int row = w * 16 + p * 8 + r8;
        gl_lds16(g + (long long)row * strideEl + cc * 8, lds + (w * 16 + p * 8) * 64);
    }
}
// Stage 16x64 bf16 tile (B for 64x16 GEMM tiles): waves 0,1 cover 8 rows each. [verified R8/R9]
__device__ inline void stageB16(const ushort* g, long long strideEl, ushort* lds, int w, int l) {
    if (w < 2) {
        int r8 = l >> 3;
        int row = w * 8 + r8;
        int cc = (l & 7) ^ (row & 7);
        gl_lds16(g + (long long)row * strideEl + cc * 8, lds + w * 512);
    }
}
__device__ inline int swz(int row, int kOff) {
    return row * 64 + ((((kOff >> 3) ^ (row & 7))) << 3);
}

// ---------------- graph preprocessing ----------------

__global__ __launch_bounds__(256) void k_init(int* __restrict__ indeg, int* __restrict__ pos) {
    int i = blockIdx.x * 256 + threadIdx.x;
    indeg[i] = 0;
    pos[i] = 0;
}

// ---------------- prep: cvt (0..2591) | transposes (2592..2751) | edge count (2752..3263) ----------------

__global__ __launch_bounds__(256) void k_prep(const float* __restrict__ text, const float* __restrict__ img,
                                              const float* __restrict__ tw, const float* __restrict__ iw,
                                              const float* __restrict__ wq, const float* __restrict__ wk,
                                              const float* __restrict__ wv, const float* __restrict__ wo,
                                              const float* __restrict__ g1w, const float* __restrict__ g2w,
                                              const int* __restrict__ edst, int* __restrict__ indeg,
                                              ushort* __restrict__ textbf, ushort* __restrict__ imgbf,
                                              ushort* __restrict__ wobf,
                                              ushort* __restrict__ twT, ushort* __restrict__ iwT,
                                              ushort* __restrict__ wqT, ushort* __restrict__ wkT,
                                              ushort* __restrict__ wvT, ushort* __restrict__ g1wT,
                                              ushort* __restrict__ g2wT) {
    __shared__ float Ts[64][65];
    const int b = blockIdx.x;
    const int t = threadIdx.x;
    if (b >= 2752) {  // edge count
        int e = (b - 2752) * 256 + t;
        atomicAdd(&indeg[edst[e]], 1);
        return;
    }
    if (b < 2592) {  // linear bf16 cvt: text | img | wo
        size_t base = ((size_t)b * 256 + t) * 8;
        const size_t TXE = (size_t)N_ * TD_, IME = (size_t)N_ * ID_;
        const float* src; ushort* dst;
        if (base < TXE) { src = text + base; dst = textbf + base; }
        else if (base < TXE + IME) { src = img + (base - TXE); dst = imgbf + (base - TXE); }
        else { src = wo + (base - TXE - IME); dst = wobf + (base - TXE - IME); }
        float4 x = *(const float4*)src;
        float4 y = *(const float4*)(src + 4);
        ushort o[8] = { f2bf(x.x), f2bf(x.y), f2bf(x.z), f2bf(x.w),
                        f2bf(y.x), f2bf(y.y), f2bf(y.z), f2bf(y.w) };
        *(short8*)dst = *(const short8*)o;
        return;
    }
    int wb = b - 2592;
    const float* src; ushort* dst; int R, tile;
    if (wb < 48)       { src = tw;  dst = twT;  R = 768; tile = wb; }
    else if (wb < 80)  { src = iw;  dst = iwT;  R = 512; tile = wb - 48; }
    else if (wb < 96)  { src = wq;  dst = wqT;  R = 256; tile = wb - 80; }
    else if (wb < 112) { src = wk;  dst = wkT;  R = 256; tile = wb - 96; }
    else if (wb < 128) { src = wv;  dst = wvT;  R = 256; tile = wb - 112; }
    else if (wb < 144) { src = g1w; dst = g1wT; R = 256; tile = wb - 128; }
    else               { src = g2w; dst = g2wT; R = 256; tile = wb - 144; }
    const int r0 = (tile >> 2) * 64, c0 = (tile & 3) * 64;
    #pragma unroll
    for (int u = 0; u < 16; u++) {
        int lin = t + u * 256;
        int r = lin >> 6, c = lin & 63;
        Ts[r][c] = src[(size_t)(r0 + r) * 256 + c0 + c];
    }
    __syncthreads();
    #pragma unroll
    for (int u = 0; u < 16; u++) {
        int lin = t + u * 256;
        int c = lin >> 6, r = lin & 63;
        dst[(size_t)(c0 + c) * R + r0 + r] = f2bf(Ts[r][c]);
    }
}

// ---------------- combined projection 64x16 tiles (blocks 0..1023) + degree scan (block 1024) ----------------

__global__ __launch_bounds__(256, 4) void k_combined16(const ushort* __restrict__ text, const ushort* __restrict__ img,
                                                       const ushort* __restrict__ twT, const ushort* __restrict__ iwT,
                                                       const float* __restrict__ tb, const float* __restrict__ ib,
                                                       const int* __restrict__ indeg, int* __restrict__ offs,
                                                       float* __restrict__ dinv, ushort* __restrict__ out) {
    __shared__ ushort As[2][4096];
    __shared__ ushort Bs[2][1024];
    __shared__ ushort Cs[64 * 24];
    __shared__ int sums[256];
    const int b = blockIdx.x;
    const int t = threadIdx.x;
    if (b == 1024) {  // exclusive scan of indeg + dinv [verified R8]
        int v[16]; int ssum = 0; int base = t * 16;
        #pragma unroll
        for (int k2 = 0; k2 < 16; k2++) { v[k2] = indeg[base + k2]; ssum += v[k2]; }
        sums[t] = ssum;
        __syncthreads();
        for (int off = 1; off < 256; off <<= 1) {
            int x = (t >= off) ? sums[t - off] : 0;
            __syncthreads();
            sums[t] += x;
            __syncthreads();
        }
        int excl = sums[t] - ssum;
        #pragma unroll
        for (int k2 = 0; k2 < 16; k2++) {
            offs[base + k2] = excl;
            excl += v[k2];
            dinv[base + k2] = 1.f / sqrtf((float)(v[k2] + 1));
        }
        return;
    }
    const int bm = (b >> 4) * 64, bn = (b & 15) * 16;
    const int w = t >> 6, l = t & 63, q = l >> 4, i = l & 15;
    f32x4 acc1 = {0, 0, 0, 0}, acc2 = {0, 0, 0, 0};
    auto stC = [&](int c, int buf) {
        if (c < 12) {
            stage64(text + (size_t)bm * TD_ + c * 64, TD_, As[buf], w, l);
            stageB16(twT + (size_t)bn * TD_ + c * 64, TD_, Bs[buf], w, l);
        } else {
            stage64(img + (size_t)bm * ID_ + (c - 12) * 64, ID_, As[buf], w, l);
            stageB16(iwT + (size_t)bn * ID_ + (c - 12) * 64, ID_, Bs[buf], w, l);
        }
    };
    stC(0, 0);
    for (int c = 0; c < 20; c++) {
        __syncthreads();
        if (c + 1 < 20) stC(c + 1, (c + 1) & 1);
        const ushort* Ab = As[c & 1];
        const ushort* Bb = Bs[c & 1];
        #pragma unroll
        for (int kb = 0; kb < 2; kb++) {
            short8 af = *(const short8*)&Ab[swz(w * 16 + i, kb * 32 + q * 8)];
            short8 bfr = *(const short8*)&Bb[swz(i, kb * 32 + q * 8)];
            if (c < 12) acc1 = MFMA16(af, bfr, acc1);
            else        acc2 = MFMA16(af, bfr, acc2);
        }
    }
    __syncthreads();
    float b1 = tb[bn + i], b2 = ib[bn + i];
    #pragma unroll
    for (int r = 0; r < 4; r++) {
        float v = fmaxf(acc1[r] + b1, 0.f) + fmaxf(acc2[r] + b2, 0.f);
        Cs[(w * 16 + q * 4 + r) * 24 + i] = f2bf(v);
    }
    __syncthreads();
    if (t < 128) {
        int row = t >> 1, h8 = (t & 1) * 8;
        *(short8*)(out + (size_t)(bm + row) * H_ + bn + h8) = *(const short8*)&Cs[row * 24 + h8];
    }
}

// ---------------- QKV (blocks 0..767) + edge scatter (768..1279) + wo-fold (1280..1296) ----------------

__global__ __launch_bounds__(256) void k_qkv_scatfold(const ushort* __restrict__ A,
                                                      const ushort* __restrict__ WqT, const ushort* __restrict__ WkT,
                                                      const ushort* __restrict__ WvT,
                                                      const float* __restrict__ bq, const float* __restrict__ bk,
                                                      const float* __restrict__ bv,
                                                      ushort* __restrict__ Qg, ushort* __restrict__ Kg,
                                                      ushort* __restrict__ Vtg,
                                                      const int* __restrict__ esrc, const int* __restrict__ edst,
                                                      const int* __restrict__ offs, const float* __restrict__ dinv,
                                                      int* __restrict__ pos, int* __restrict__ ssrc,
                                                      float* __restrict__ swv,
                                                      const ushort* __restrict__ g1wT, const ushort* __restrict__ wobf,
                                                      const float* __restrict__ bo,
                                                      ushort* __restrict__ WpT, float* __restrict__ bp) {
    __shared__ ushort As[2][4096];
    __shared__ ushort Bs[2][4096];
    __shared__ ushort Cs[64 * 72];
    const int b = blockIdx.x;
    const int t = threadIdx.x;
    const int w = t >> 6, l = t & 63, q = l >> 4, i = l & 15;

    if (b >= 768) {
        if (b < 1280) {  // edge scatter
            int e = (b - 768) * 256 + t;
            int s = esrc[e], d = edst[e];
            int p = atomicAdd(&pos[d], 1);
            int idx = offs[d] + p;
            ssrc[idx] = s;
            swv[idx] = dinv[s] * dinv[d];
            return;
        }
        if (b == 1296) {  // bp[c] = sum_m bo[m] * g1wT[c][m]
            float acc = 0.f;
            const ushort* row = g1wT + (size_t)t * 256;
            for (int m8 = 0; m8 < 256; m8 += 8) {
                #pragma unroll
                for (int j = 0; j < 8; j++) acc += bo[m8 + j] * lo2f(((unsigned)row[m8 + j]) << 16);
            }
            bp[t] = acc;
            return;
        }
        // wo-fold tile: WpT[a][b2] = sum_m g1wT[a][m]*wobf[b2][m]
        const int f = b - 1280;
        const int bm = (f >> 2) * 64, bn = (f & 3) * 64;
        f32x4 acc[4];
        #pragma unroll
        for (int nt = 0; nt < 4; nt++) acc[nt] = (f32x4){0, 0, 0, 0};
        stage64(g1wT + (size_t)bm * H_, H_, As[0], w, l);
        stage64(wobf + (size_t)bn * H_, H_, Bs[0], w, l);
        for (int c = 0; c < 4; c++) {
            __syncthreads();
            if (c < 3) {
                stage64(g1wT + (size_t)bm * H_ + (c + 1) * 64, H_, As[(c + 1) & 1], w, l);
                stage64(wobf + (size_t)bn * H_ + (c + 1) * 64, H_, Bs[(c + 1) & 1], w, l);
            }
            const ushort* Ab = As[c & 1];
            const ushort* Bb = Bs[c & 1];
            #pragma unroll
            for (int kb = 0; kb < 2; kb++) {
                short8 af = *(const short8*)&Ab[swz(w * 16 + i, kb * 32 + q * 8)];
                #pragma unroll
                for (int nt = 0; nt < 4; nt++) {
                    short8 bfr = *(const short8*)&Bb[swz(nt * 16 + i, kb * 32 + q * 8)];
                    acc[nt] = MFMA16(af, bfr, acc[nt]);
                }
            }
        }
        __syncthreads();
        #pragma unroll
        for (int nt = 0; nt < 4; nt++)
            #pragma unroll
            for (int r = 0; r < 4; r++)
                Cs[(w * 16 + q * 4 + r) * 72 + nt * 16 + i] = f2bf(acc[nt][r]);
        __syncthreads();
        int rr = t >> 2, c16 = (t & 3) * 16;
        short8 v0 = *(const short8*)&Cs[rr * 72 + c16];
        short8 v1 = *(const short8*)&Cs[rr * 72 + c16 + 8];
        ushort* dstp = WpT + (size_t)(bm + rr) * H_ + bn + c16;
        *(short8*)dstp = v0;
        *(short8*)(dstp + 8) = v1;
        return;
    }

    // QKV: z = b>>8, rem = b&255 [verified R8]
    const int z = b >> 8, rem = b & 255;
    const int bm = (rem >> 2) * 64, head = rem & 3;
    const ushort* WT = (z == 0) ? WqT : (z == 1) ? WkT : WvT;
    const float* bias = (z == 0) ? bq : (z == 1) ? bk : bv;
    f32x4 acc[4];
    #pragma unroll
    for (int nt = 0; nt < 4; nt++) acc[nt] = (f32x4){0, 0, 0, 0};

    stage64(A + (size_t)bm * H_, H_, As[0], w, l);
    stage64(WT + (size_t)(head * 64) * H_, H_, Bs[0], w, l);
    for (int c = 0; c < 4; c++) {
        __syncthreads();
        if (c < 3) {
            stage64(A + (size_t)bm * H_ + (c + 1) * 64, H_, As[(c + 1) & 1], w, l);
            stage64(WT + (size_t)(head * 64) * H_ + (c + 1) * 64, H_, Bs[(c + 1) & 1], w, l);
        }
        const ushort* Ab = As[c & 1];
        const ushort* Bb = Bs[c & 1];
        #pragma unroll
        for (int kb = 0; kb < 2; kb++) {
            short8 af = *(const short8*)&Ab[swz(w * 16 + i, kb * 32 + q * 8)];
            #pragma unroll
            for (int nt = 0; nt < 4; nt++) {
                short8 bfr = *(const short8*)&Bb[swz(nt * 16 + i, kb * 32 + q * 8)];
                acc[nt] = MFMA16(af, bfr, acc[nt]);
            }
        }
    }
    __syncthreads();
    #pragma unroll
    for (int nt = 0; nt < 4; nt++) {
        float bv_ = bias[head * 64 + nt * 16 + i];
        #pragma unroll
        for (int r = 0; r < 4; r++) {
            float v = acc[nt][r] + bv_;
            if (z == 0) v *= QSCALE;
            if (z < 2) Cs[(w * 16 + q * 4 + r) * 72 + nt * 16 + i] = f2bf(v);
            else       Cs[(nt * 16 + i) * 72 + w * 16 + q * 4 + r] = f2bf(v);  // transposed [d][n]
        }
    }
    __syncthreads();
    int rr = t >> 2, c16 = (t & 3) * 16;
    short8 v0 = *(const short8*)&Cs[rr * 72 + c16];
    short8 v1 = *(const short8*)&Cs[rr * 72 + c16 + 8];
    ushort* dst;
    if (z < 2) dst = ((z == 0) ? Qg : Kg) + (size_t)head * N_ * HD_ + (size_t)(bm + rr) * HD_ + c16;
    else       dst = Vtg + (size_t)head * HD_ * N_ + (size_t)rr * N_ + bm + c16;
    *(short8*)dst = v0;
    *(short8*)(dst + 8) = v1;
}

// ---------------- flash attention: S^T math, single-buf K/V, split-16, 128 queries/block ----------------
// 128 queries amortize each staged K/V tile over 2 query tiles (R12 efficiency win); SPLITS=16
// restores the 2048-block grid (R4/R11 parallelism level). Ps reused sequentially per query tile.

__global__ __launch_bounds__(256) void k_attn_mfma(const ushort* __restrict__ Qg, const ushort* __restrict__ Kg,
                                                   const ushort* __restrict__ Vtg, ushort* __restrict__ Op,
                                                   float* __restrict__ lp) {
    __shared__ ushort Ks[4096];
    __shared__ ushort Vs[4096];
    __shared__ ushort Ps[4][16 * 72];
    const int head = blockIdx.y, r0 = blockIdx.x * 128, z = blockIdx.z;
    const int t = threadIdx.x, w = t >> 6, l = t & 63, q = l >> 4, i = l & 15;
    const int rw = (i ^ (i >> 1)) & 7;
    ushort* Pw = &Ps[w][0];

    short8 qf[2][2];  // [qt][kb]
    #pragma unroll
    for (int qt = 0; qt < 2; qt++)
        #pragma unroll
        for (int kb = 0; kb < 2; kb++)
            qf[qt][kb] = *(const short8*)(Qg + ((size_t)head * N_ + r0 + qt * 64 + w * 16 + i) * HD_ + kb * 32 + q * 8);

    f32x4 Oacc[2][4];
    float lacc[2] = {0.f, 0.f};
    #pragma unroll
    for (int qt = 0; qt < 2; qt++)
        #pragma unroll
        for (int dt = 0; dt < 4; dt++) Oacc[qt][dt] = (f32x4){0, 0, 0, 0};

    const int NT = 64 / SPLITS;
    const int cb0 = z * NT;
    for (int it = 0; it < NT; it++) {
        const int cb = cb0 + it;
        __syncthreads();
        stage64(Kg + ((size_t)head * N_ + (size_t)cb * 64) * HD_, HD_, Ks, w, l);
        stage64(Vtg + (size_t)head * HD_ * N_ + cb * 64, N_, Vs, w, l);
        __syncthreads();

        // S^T for both query tiles; kf loaded once, used twice
        f32x4 St[2][4];
        #pragma unroll
        for (int qt = 0; qt < 2; qt++)
            #pragma unroll
            for (int kt = 0; kt < 4; kt++) St[qt][kt] = (f32x4){0, 0, 0, 0};
        #pragma unroll
        for (int kb = 0; kb < 2; kb++) {
            #pragma unroll
            for (int kt = 0; kt < 4; kt++) {
                short8 kf = *(const short8*)&Ks[swz(kt * 16 + i, kb * 32 + q * 8)];
                St[0][kt] = MFMA16(kf, qf[0][kb], St[0][kt]);
                St[1][kt] = MFMA16(kf, qf[1][kb], St[1][kt]);
            }
        }
        // per query tile: exp -> pack -> Ps -> PV
        #pragma unroll
        for (int qt = 0; qt < 2; qt++) {
            #pragma unroll
            for (int kt = 0; kt < 4; kt++) {
                float p0 = exp2r(St[qt][kt][0]), p1 = exp2r(St[qt][kt][1]);
                float p2 = exp2r(St[qt][kt][2]), p3 = exp2r(St[qt][kt][3]);
                lacc[qt] += (p0 + p1) + (p2 + p3);
                int off = i * 72 + (((2 * kt + (q >> 1)) ^ rw) << 3) + ((q & 1) << 2);
                uint2 v; v.x = pkbf(p0, p1); v.y = pkbf(p2, p3);
                *(uint2*)&Pw[off] = v;
            }
            #pragma unroll
            for (int kb = 0; kb < 2; kb++) {
                short8 pf = *(const short8*)&Pw[i * 72 + (((4 * kb + q) ^ rw) << 3)];
                #pragma unroll
                for (int dt = 0; dt < 4; dt++) {
                    short8 vf = *(const short8*)&Vs[swz(dt * 16 + i, kb * 32 + q * 8)];
                    Oacc[qt][dt] = MFMA16(vf, pf, Oacc[qt][dt]);
                }
            }
        }
    }

    #pragma unroll
    for (int qt = 0; qt < 2; qt++) {
        lacc[qt] += __shfl_xor(lacc[qt], 16);
        lacc[qt] += __shfl_xor(lacc[qt], 32);
    }

    const size_t sh = ((size_t)z * 4 + head) * N_;
    #pragma unroll
    for (int qt = 0; qt < 2; qt++) {
        const int row = r0 + qt * 64 + w * 16 + i;
        #pragma unroll
        for (int dt = 0; dt < 4; dt++) {
            uint2 v;
            v.x = pkbf(Oacc[qt][dt][0], Oacc[qt][dt][1]);
            v.y = pkbf(Oacc[qt][dt][2], Oacc[qt][dt][3]);
            *(uint2*)&Op[(sh + row) * HD_ + dt * 16 + q * 4] = v;
        }
        if (l < 16) lp[sh + r0 + qt * 64 + w * 16 + l] = lacc[qt];
    }
}

// merge 16 splits -> obuf bf16 [N][H]
__global__ __launch_bounds__(256) void k_attn_merge(const ushort* __restrict__ Op, const float* __restrict__ lp,
                                                    ushort* __restrict__ obuf) {
    const int t = threadIdx.x;
    const int idx = blockIdx.x * 16 + (t >> 4);
    const int h = idx >> 12, n = idx & 4095;
    const int d4 = (t & 15) * 4;
    float lsum = 0.f;
    float acc[4] = {0.f, 0.f, 0.f, 0.f};
    #pragma unroll
    for (int s = 0; s < SPLITS; s++) {
        size_t sh = ((size_t)s * 4 + h) * N_ + n;
        lsum += lp[sh];
        uint2 o4 = *(const uint2*)&Op[sh * HD_ + d4];
        acc[0] += lo2f(o4.x); acc[1] += hi2f(o4.x);
        acc[2] += lo2f(o4.y); acc[3] += hi2f(o4.y);
    }
    float inv = 1.f / lsum;
    uint2 res;
    res.x = pkbf(acc[0] * inv, acc[1] * inv);
    res.y = pkbf(acc[2] * inv, acc[3] * inv);
    *(uint2*)&obuf[(size_t)n * H_ + h * HD_ + d4] = res;
}

// ---------------- bf16 MFMA GEMM, 64x16 tiles (grid 64x16) [verified R9] ----------------

template <bool BIAS>
__global__ __launch_bounds__(256, 4) void k_gemm16(const ushort* __restrict__ A, const ushort* __restrict__ BT,
                                                   const float* __restrict__ bias, ushort* __restrict__ outb) {
    __shared__ ushort As[2][4096];
    __shared__ ushort Bs[2][1024];
    __shared__ ushort Cs[64 * 24];
    const int bm = blockIdx.x * 64, bn = blockIdx.y * 16;
    const int t = threadIdx.x, w = t >> 6, l = t & 63, q = l >> 4, i = l & 15;
    f32x4 acc = {0, 0, 0, 0};
    stage64(A + (size_t)bm * H_, H_, As[0], w, l);
    stageB16(BT + (size_t)bn * H_, H_, Bs[0], w, l);
    for (int c = 0; c < 4; c++) {
        __syncthreads();
        if (c < 3) {
            stage64(A + (size_t)bm * H_ + (c + 1) * 64, H_, As[(c + 1) & 1], w, l);
            stageB16(BT + (size_t)bn * H_ + (c + 1) * 64, H_, Bs[(c + 1) & 1], w, l);
        }
        const ushort* Ab = As[c & 1];
        const ushort* Bb = Bs[c & 1];
        #pragma unroll
        for (int kb = 0; kb < 2; kb++) {
            short8 af = *(const short8*)&Ab[swz(w * 16 + i, kb * 32 + q * 8)];
            short8 bfr = *(const short8*)&Bb[swz(i, kb * 32 + q * 8)];
            acc = MFMA16(af, bfr, acc);
        }
    }
    __syncthreads();
    float bb = BIAS ? bias[bn + i] : 0.f;
    #pragma unroll
    for (int r = 0; r < 4; r++)
        Cs[(w * 16 + q * 4 + r) * 24 + i] = f2bf(acc[r] + bb);
    __syncthreads();
    if (t < 128) {
        int row = t >> 1, h8 = (t & 1) * 8;
        *(short8*)(outb + (size_t)(bm + row) * H_ + bn + h8) = *(const short8*)&Cs[row * 24 + h8];
    }
}

// ---------------- GCN aggregation: one wave per node, 4 nodes/block ----------------

__global__ __launch_bounds__(256) void k_agg1(const ushort* __restrict__ h, const int* __restrict__ ssrc,
                                              const float* __restrict__ sw, const int* __restrict__ offs,
                                              const int* __restrict__ indeg, const float* __restrict__ dinv,
                                              const float* __restrict__ bias, ushort* __restrict__ outb) {
    const int t = threadIdx.x;
    const int j = __builtin_amdgcn_readfirstlane(blockIdx.x * 4 + (t >> 6));
    const int d0 = (t & 63) * 4;
    float dj = dinv[j];
    uint2 hv = *(const uint2*)&h[(size_t)j * H_ + d0];
    float s2 = dj * dj;
    float a0 = s2 * lo2f(hv.x), a1 = s2 * hi2f(hv.x), a2 = s2 * lo2f(hv.y), a3 = s2 * hi2f(hv.y);
    int start = offs[j], cnt = indeg[j];
    for (int e = 0; e < cnt; e++) {
        int s = ssrc[start + e];
        float wg = sw[start + e];
        uint2 v = *(const uint2*)&h[(size_t)s * H_ + d0];
        a0 += wg * lo2f(v.x); a1 += wg * hi2f(v.x);
        a2 += wg * lo2f(v.y); a3 += wg * hi2f(v.y);
    }
    a0 = fmaxf(a0 + bias[d0], 0.f);
    a1 = fmaxf(a1 + bias[d0 + 1], 0.f);
    a2 = fmaxf(a2 + bias[d0 + 2], 0.f);
    a3 = fmaxf(a3 + bias[d0 + 3], 0.f);
    uint2 o;
    o.x = pkbf(a0, a1);
    o.y = pkbf(a2, a3);
    *(uint2*)&outb[(size_t)j * H_ + d0] = o;
}

// ---------------- GCN layer 2 aggregation fused with classifier ----------------

__global__ __launch_bounds__(256) void k_aggcls(const ushort* __restrict__ h, const int* __restrict__ ssrc,
                                                const float* __restrict__ sw, const int* __restrict__ offs,
                                                const int* __restrict__ indeg, const float* __restrict__ dinv,
                                                const float* __restrict__ bias, const float* __restrict__ cw,
                                                const float* __restrict__ cb, float* __restrict__ out) {
    const int t = threadIdx.x;
    const int j = __builtin_amdgcn_readfirstlane(blockIdx.x * 4 + (t >> 6));
    const int lane = t & 63;
    const int d0 = lane * 4;
    float dj = dinv[j];
    uint2 hv = *(const uint2*)&h[(size_t)j * H_ + d0];
    float s2 = dj * dj;
    float a0 = s2 * lo2f(hv.x), a1 = s2 * hi2f(hv.x), a2 = s2 * lo2f(hv.y), a3 = s2 * hi2f(hv.y);
    int start = offs[j], cnt = indeg[j];
    for (int e = 0; e < cnt; e++) {
        int s = ssrc[start + e];
        float wg = sw[start + e];
        uint2 v = *(const uint2*)&h[(size_t)s * H_ + d0];
        a0 += wg * lo2f(v.x); a1 += wg * hi2f(v.x);
        a2 += wg * lo2f(v.y); a3 += wg * hi2f(v.y);
    }
    a0 += bias[d0]; a1 += bias[d0 + 1]; a2 += bias[d0 + 2]; a3 += bias[d0 + 3];
    float p0 = a0 * cw[d0 * 3 + 0] + a1 * cw[(d0 + 1) * 3 + 0]
             + a2 * cw[(d0 + 2) * 3 + 0] + a3 * cw[(d0 + 3) * 3 + 0];
    float p1 = a0 * cw[d0 * 3 + 1] + a1 * cw[(d0 + 1) * 3 + 1]
             + a2 * cw[(d0 + 2) * 3 + 1] + a3 * cw[(d0 + 3) * 3 + 1];
    float p2 = a0 * cw[d0 * 3 + 2] + a1 * cw[(d0 + 1) * 3 + 2]
             + a2 * cw[(d0 + 2) * 3 + 2] + a3 * cw[(d0 + 3) * 3 + 2];
    #pragma unroll
    for (int off = 32; off > 0; off >>= 1) {
        p0 += __shfl_xor(p0, off);
        p1 += __shfl_xor(p1, off);
        p2 += __shfl_xor(p2, off);
    }
    if (lane == 0) {
        out[j * 3 + 0] = p0 + cb[0];
        out[j * 3 + 1] = p1 + cb[1];
        out[j * 3 + 2] = p2 + cb[2];
    }
}

// ---------------- launch ----------------

extern "C" void kernel_launch(void* const* d_in, const int* in_sizes, int n_in,
                              void* d_out, int out_size, void* d_ws, size_t ws_size,
                              hipStream_t stream) {
    const float* text = (const float*)d_in[0];
    const float* img  = (const float*)d_in[1];
    const int*   eidx = (const int*)d_in[2];
    const float* tw  = (const float*)d_in[3];
    const float* tb  = (const float*)d_in[4];
    const float* iw  = (const float*)d_in[5];
    const float* ib  = (const float*)d_in[6];
    const float* wq  = (const float*)d_in[7];
    const float* bq  = (const float*)d_in[8];
    const float* wk  = (const float*)d_in[9];
    const float* bk  = (const float*)d_in[10];
    const float* wv  = (const float*)d_in[11];
    const float* bv  = (const float*)d_in[12];
    const float* wo  = (const float*)d_in[13];
    const float* bo  = (const float*)d_in[14];
    const float* g1w = (const float*)d_in[15];
    const float* g1b = (const float*)d_in[16];
    const float* g2w = (const float*)d_in[17];
    const float* g2b = (const float*)d_in[18];
    const float* cw  = (const float*)d_in[19];
    const float* cbv = (const float*)d_in[20];

    char* W = (char*)d_ws;
    size_t cur = 0;
    auto alloc = [&](size_t sz) { char* p = W + cur; cur += (sz + 255) & ~(size_t)255; return p; };

    // persistent region
    float* dinv  = (float*)alloc(N_ * 4);
    float* swv   = (float*)alloc(E_ * 4);
    int* indeg   = (int*)alloc(N_ * 4);
    int* offs    = (int*)alloc(N_ * 4);
    int* pos     = (int*)alloc(N_ * 4);
    int* ssrc    = (int*)alloc(E_ * 4);
    ushort* Qg   = (ushort*)alloc((size_t)N_ * H_ * 2);
    ushort* Kg   = (ushort*)alloc((size_t)N_ * H_ * 2);
    ushort* Vtg  = (ushort*)alloc((size_t)N_ * H_ * 2);
    ushort* obuf = (ushort*)alloc((size_t)N_ * H_ * 2);
    ushort* WpT  = (ushort*)alloc((size_t)H_ * H_ * 2);
    float* bp    = (float*)alloc(H_ * 4);
    ushort* g1wT = (ushort*)alloc((size_t)H_ * H_ * 2);
    ushort* g2wT = (ushort*)alloc((size_t)H_ * H_ * 2);
    ushort* wobf = (ushort*)alloc((size_t)H_ * H_ * 2);
    float* lp    = (float*)alloc((size_t)SPLITS * 4 * N_ * 4);
    char* S = W + cur;  // phase-overlaid scratch

    // phase 1: conversions + projections (~13 MB)
    ushort* textbf = (ushort*)S;
    ushort* imgbf  = textbf + (size_t)N_ * TD_;
    ushort* twT    = imgbf + (size_t)N_ * ID_;
    ushort* iwT    = twT + (size_t)TD_ * H_;
    ushort* wqT    = iwT + (size_t)ID_ * H_;
    ushort* wkT    = wqT + (size_t)H_ * H_;
    ushort* wvT    = wkT + (size_t)H_ * H_;
    ushort* combbf = wvT + (size_t)H_ * H_;
    // phase 2: Op = 16*4*N*64 bf16 = 32 MB (overlays phase 1)
    ushort* Op = (ushort*)S;
    // phase 3: post-attention (Op dead after merge)
    ushort* hbuf  = (ushort*)S;
    ushort* g1b16 = (ushort*)(S + (size_t)2 * 1024 * 1024);
    ushort* hbuf2 = (ushort*)(S + (size_t)4 * 1024 * 1024);

    const int* esrc = eidx;
    const int* edst = eidx + E_;

    k_init<<<dim3(N_ / 256), dim3(256), 0, stream>>>(indeg, pos);
    k_prep<<<dim3(3264), dim3(256), 0, stream>>>(text, img, tw, iw, wq, wk, wv, wo, g1w, g2w,
                                                 edst, indeg,
                                                 textbf, imgbf, wobf, twT, iwT, wqT, wkT, wvT, g1wT, g2wT);
    k_combined16<<<dim3(1025), dim3(256), 0, stream>>>(textbf, imgbf, twT, iwT, tb, ib,
                                                       indeg, offs, dinv, combbf);
    k_qkv_scatfold<<<dim3(1297), dim3(256), 0, stream>>>(combbf, wqT, wkT, wvT, bq, bk, bv, Qg, Kg, Vtg,
                                                         esrc, edst, offs, dinv, pos, ssrc, swv,
                                                         g1wT, wobf, bo, WpT, bp);
    k_attn_mfma<<<dim3(32, 4, SPLITS), dim3(256), 0, stream>>>(Qg, Kg, Vtg, Op, lp);
    k_attn_merge<<<dim3(1024), dim3(256), 0, stream>>>(Op, lp, obuf);

    k_gemm16<true><<<dim3(64, 16), dim3(256), 0, stream>>>(obuf, WpT, bp, hbuf);
    k_agg1<<<dim3(N_ / 4), dim3(256), 0, stream>>>(hbuf, ssrc, swv, offs, indeg, dinv, g1b, g1b16);
    k_gemm16<false><<<dim3(64, 16), dim3(256), 0, stream>>>(g1b16, g2wT, nullptr, hbuf2);
    k_aggcls<<<dim3(N_ / 4), dim3(256), 0, stream>>>(hbuf2, ssrc, swv, offs, indeg, dinv, g2b, cw, cbv,
                                                     (float*)d_out);
}